// Round 4
// baseline (311.514 us; speedup 1.0000x reference)
//
#include <hip/hip_runtime.h>
#include <math.h>

#define BB 8
#define SS 4096
#define DD 64
#define NTH 32   // tiles per half-sweep (64 k each)

typedef float  f32x4 __attribute__((ext_vector_type(4)));
typedef short  s16x4 __attribute__((ext_vector_type(4)));
typedef short  s16x8 __attribute__((ext_vector_type(8)));
typedef unsigned char u8x16 __attribute__((ext_vector_type(16)));

__device__ __forceinline__ short f2bf(float f) {
  unsigned u = __builtin_bit_cast(unsigned, f);
  u += 0x7FFFu + ((u >> 16) & 1u);
  return (short)(u >> 16);
}

// ---------------- kernel 1: L2-normalize q,k rows -> bf16 ----------------
__global__ __launch_bounds__(256) void k_norm(const float* __restrict__ q,
                                              const float* __restrict__ k,
                                              short* __restrict__ qn,
                                              short* __restrict__ kn) {
  const long BS = (long)BB * SS;
  long row = (long)blockIdx.x * 4 + (threadIdx.x >> 6);
  int lane = threadIdx.x & 63;
  const float* src;
  short* dst;
  if (row < BS) { src = q + row * DD; dst = qn + row * DD; }
  else          { src = k + (row - BS) * DD; dst = kn + (row - BS) * DD; }
  float x = src[lane];
  float ss = x * x;
#pragma unroll
  for (int m = 32; m >= 1; m >>= 1) ss += __shfl_xor(ss, m);
  float inv = 1.0f / (sqrtf(ss) + 1e-10f);
  dst[lane] = f2bf(x * inv);
}

// ---------------- kernel 2: V -> VT[b][d][s] bf16 ----------------
__global__ __launch_bounds__(256) void k_vtrans(const float* __restrict__ v,
                                                short* __restrict__ vt) {
  __shared__ short tile[64][65];
  int b = blockIdx.y;
  int s0 = blockIdx.x * 64;
  const float* V = v + ((long)b * SS + s0) * DD;
  int t = threadIdx.x;
#pragma unroll
  for (int i = 0; i < 16; i++) {
    int flat = t + 256 * i;            // flat = sl*64 + d
    int sl = flat >> 6, d = flat & 63;
    tile[sl][d] = f2bf(V[flat]);
  }
  __syncthreads();
  short* VT = vt + (long)b * DD * SS + s0;
#pragma unroll
  for (int i = 0; i < 16; i++) {
    int flat = t + 256 * i;            // flat = d*64 + sl
    int d = flat >> 6, sl = flat & 63;
    VT[(long)d * SS + sl] = tile[sl][d];
  }
}

// ------- pass A (k-split x2): mask->bits + partial exp row-sums -------
// 4 waves/block, wave = 16 q rows, half K sweep. Streams raw mask, packs to
// bits (1 KB LDS dbuf for own masking + global store for pass B), atomically
// accumulates exp row-sums into accG.
__global__ __launch_bounds__(256) void k_rowsum(const short* __restrict__ qn,
                                                const short* __restrict__ kn,
                                                const unsigned char* __restrict__ mask,
                                                unsigned short* __restrict__ bits16,
                                                float* __restrict__ accG) {
  __shared__ __align__(16) short Kt[2][4096];                 // 16 KB
  __shared__ __align__(16) unsigned long long bitsT[2][64];   // 1 KB
  int b = blockIdx.x & 7;
  int half = (blockIdx.x >> 3) & 1;
  int q0 = (blockIdx.x >> 4) << 6;
  int t0 = half * NTH;
  int wid = threadIdx.x >> 6, lane = threadIdx.x & 63;
  int l15 = lane & 15, g = lane >> 4;
  int qr = q0 + (wid << 4);

  const short* Qr = qn + ((long)(b * SS) + qr + l15) * DD;
  s16x8 qf0 = *(const s16x8*)(Qr + 8 * g);
  s16x8 qf1 = *(const s16x8*)(Qr + 32 + 8 * g);

  const short* Kb = kn + (long)b * SS * DD + (long)t0 * 64 * DD;

  int sr = lane >> 3, sc = lane & 7;
  int r0 = (wid << 4) + sr, r1 = r0 + 8;
  const short* Ksrc0 = Kb + (long)r0 * DD + sc * 8;
  const short* Ksrc1 = Kb + (long)r1 * DD + sc * 8;
  int sd0 = r0 * DD + ((sc ^ sr) << 3);
  int sd1 = r1 * DD + ((sc ^ sr) << 3);
  int swk = l15 & 7;

  // mask pipeline: lane packs 16 bytes of row mrow, piece mpiece
  int mrow = (wid << 4) + (lane >> 2);
  int mpiece = lane & 3;
  const unsigned char* Msrc = mask + ((long)(b * SS) + q0 + mrow) * SS + t0 * 64 + mpiece * 16;
  unsigned short* Bdst = bits16 + ((long)(b * SS) + q0 + mrow) * (SS / 16) + mpiece;
  unsigned short* bT16 = (unsigned short*)bitsT;

  // prologue: tile 0
  u8x16 mCur = __builtin_nontemporal_load((const u8x16*)Msrc);
  u8x16 mNext = __builtin_nontemporal_load((const u8x16*)(Msrc + 64));
  s16x8 kst0 = *(const s16x8*)Ksrc0;
  s16x8 kst1 = *(const s16x8*)Ksrc1;
  {
    unsigned bv = 0;
#pragma unroll
    for (int i = 0; i < 16; i++) bv |= (mCur[i] ? 1u : 0u) << i;
    bT16[(0 * 64 + mrow) * 4 + mpiece] = (unsigned short)bv;
    __builtin_nontemporal_store((unsigned short)bv, Bdst + (long)(t0) * 4);
  }
  *(s16x8*)&Kt[0][sd0] = kst0;
  *(s16x8*)&Kt[0][sd1] = kst1;
  __syncthreads();

  float acc = 0.f;
  int cur = 0;
  for (int t = 0; t < NTH; ++t) {
    if (t + 1 < NTH) {
      long koff = (long)(t + 1) * 64 * DD;
      kst0 = *(const s16x8*)(Ksrc0 + koff);
      kst1 = *(const s16x8*)(Ksrc1 + koff);
    }
    u8x16 mFar = mNext;
    if (t + 2 < NTH)
      mFar = __builtin_nontemporal_load((const u8x16*)(Msrc + (long)(t + 2) * 64));
    if (t + 1 < NTH) {
      unsigned bv = 0;
#pragma unroll
      for (int i = 0; i < 16; i++) bv |= (mNext[i] ? 1u : 0u) << i;
      bT16[((cur ^ 1) * 64 + mrow) * 4 + mpiece] = (unsigned short)bv;
      __builtin_nontemporal_store((unsigned short)bv, Bdst + (long)(t0 + t + 1) * 4);
    }
    unsigned long long w64 = bitsT[cur][(wid << 4) + l15];   // wave-local rows
    const short* Kc = &Kt[cur][0];
#pragma unroll
    for (int tt = 0; tt < 4; ++tt) {
      const short* krow = Kc + ((tt << 4) + l15) * DD;
      s16x8 a0 = *(const s16x8*)(krow + ((g ^ swk) << 3));
      s16x8 a1 = *(const s16x8*)(krow + (((4 + g) ^ swk) << 3));
      f32x4 c = {0.f, 0.f, 0.f, 0.f};
      c = __builtin_amdgcn_mfma_f32_16x16x32_bf16(a0, qf0, c, 0, 0, 0);
      c = __builtin_amdgcn_mfma_f32_16x16x32_bf16(a1, qf1, c, 0, 0, 0);
#pragma unroll
      for (int r = 0; r < 4; ++r) {
        unsigned bit = (unsigned)(w64 >> ((tt << 4) + (g << 2) + r)) & 1u;
        acc += bit ? 0.f : __expf(c[r]);
      }
    }
    if (t + 1 < NTH) {
      short* Kd = &Kt[cur ^ 1][0];
      *(s16x8*)(Kd + sd0) = kst0;
      *(s16x8*)(Kd + sd1) = kst1;
    }
    __syncthreads();
    cur ^= 1;
    mNext = mFar;
  }
  acc += __shfl_xor(acc, 16);
  acc += __shfl_xor(acc, 32);
  if (lane < 16) atomicAdd(&accG[(long)b * SS + qr + l15], acc);
}

// ------- pass B (k-split x2): recompute scores, write P, accumulate O -------
__global__ __launch_bounds__(256) void k_attn(const short* __restrict__ qn,
                                              const short* __restrict__ kn,
                                              const short* __restrict__ vt,
                                              const unsigned short* __restrict__ bits16,
                                              const float* __restrict__ accG,
                                              float* __restrict__ O,
                                              float* __restrict__ P) {
  __shared__ __align__(16) short Kt[2][4096];   // 16 KB
  __shared__ __align__(16) short Vt[2][4096];   // 16 KB
  int b = blockIdx.x & 7;
  int half = (blockIdx.x >> 3) & 1;
  int q0 = (blockIdx.x >> 4) << 6;
  int t0 = half * NTH;
  int wid = threadIdx.x >> 6, lane = threadIdx.x & 63;
  int l15 = lane & 15, g = lane >> 4;
  int qr = q0 + (wid << 4);

  const short* Qr = qn + ((long)(b * SS) + qr + l15) * DD;
  s16x8 qf0 = *(const s16x8*)(Qr + 8 * g);
  s16x8 qf1 = *(const s16x8*)(Qr + 32 + 8 * g);

  const short* Kb = kn + (long)b * SS * DD + (long)t0 * 64 * DD;
  const short* Vb = vt + (long)b * DD * SS + t0 * 64;
  const unsigned long long* B64 =
      (const unsigned long long*)bits16 + ((long)(b * SS) + qr + l15) * (SS / 64);
  float linv = -__logf(accG[(long)b * SS + qr + l15]);
  float* Prow = P + ((long)(b * SS) + qr + l15) * SS;

  int sr = lane >> 3, sc = lane & 7;
  int r0 = (wid << 4) + sr, r1 = r0 + 8;
  const short* Ksrc0 = Kb + (long)r0 * DD + sc * 8;
  const short* Ksrc1 = Kb + (long)r1 * DD + sc * 8;
  const short* Vsrc0 = Vb + (long)r0 * SS + sc * 8;
  const short* Vsrc1 = Vb + (long)r1 * SS + sc * 8;
  int sd0 = r0 * DD + ((sc ^ sr) << 3);
  int sd1 = r1 * DD + ((sc ^ sr) << 3);
  int swk = l15 & 7;

  // prologue: stage tile 0
  s16x8 kst0 = *(const s16x8*)Ksrc0;
  s16x8 kst1 = *(const s16x8*)Ksrc1;
  s16x8 vst0 = *(const s16x8*)Vsrc0;
  s16x8 vst1 = *(const s16x8*)Vsrc1;
  *(s16x8*)&Kt[0][sd0] = kst0;
  *(s16x8*)&Kt[0][sd1] = kst1;
  *(s16x8*)&Vt[0][sd0] = vst0;
  *(s16x8*)&Vt[0][sd1] = vst1;
  __syncthreads();

  f32x4 o0 = {0, 0, 0, 0}, o1 = {0, 0, 0, 0}, o2 = {0, 0, 0, 0}, o3 = {0, 0, 0, 0};
  int cur = 0;
  for (int t = 0; t < NTH; ++t) {
    if (t + 1 < NTH) {
      long koff = (long)(t + 1) * 64 * DD;
      kst0 = *(const s16x8*)(Ksrc0 + koff);
      kst1 = *(const s16x8*)(Ksrc1 + koff);
      vst0 = *(const s16x8*)(Vsrc0 + (t + 1) * 64);
      vst1 = *(const s16x8*)(Vsrc1 + (t + 1) * 64);
    }
    unsigned long long w64 = B64[t0 + t];
    const short* Kc = &Kt[cur][0];
    const short* Vc = &Vt[cur][0];

    f32x4 p[4];
#pragma unroll
    for (int tt = 0; tt < 4; ++tt) {
      const short* krow = Kc + ((tt << 4) + l15) * DD;
      s16x8 a0 = *(const s16x8*)(krow + ((g ^ swk) << 3));
      s16x8 a1 = *(const s16x8*)(krow + (((4 + g) ^ swk) << 3));
      f32x4 c = {0.f, 0.f, 0.f, 0.f};
      c = __builtin_amdgcn_mfma_f32_16x16x32_bf16(a0, qf0, c, 0, 0, 0);
      c = __builtin_amdgcn_mfma_f32_16x16x32_bf16(a1, qf1, c, 0, 0, 0);
#pragma unroll
      for (int r = 0; r < 4; ++r) {
        unsigned bit = (unsigned)(w64 >> ((tt << 4) + (g << 2) + r)) & 1u;
        p[tt][r] = bit ? 0.f : __expf(c[r] + linv);
      }
      __builtin_nontemporal_store(p[tt],
          (f32x4*)(Prow + ((t0 + t) << 6) + (tt << 4) + (g << 2)));
    }

    s16x8 pa0, pa1;
#pragma unroll
    for (int j = 0; j < 4; ++j) {
      pa0[j] = f2bf(p[0][j]); pa0[4 + j] = f2bf(p[1][j]);
      pa1[j] = f2bf(p[2][j]); pa1[4 + j] = f2bf(p[3][j]);
    }

#pragma unroll
    for (int n = 0; n < 4; ++n) {
      const short* vrow = Vc + ((n << 4) + l15) * DD;
      int g2 = g >> 1, hh = (g & 1) << 2;
      s16x4 lo0 = *(const s16x4*)(vrow + (((g2    ) ^ swk) << 3) + hh);
      s16x4 hi0 = *(const s16x4*)(vrow + (((g2 + 2) ^ swk) << 3) + hh);
      s16x4 lo1 = *(const s16x4*)(vrow + (((g2 + 4) ^ swk) << 3) + hh);
      s16x4 hi1 = *(const s16x4*)(vrow + (((g2 + 6) ^ swk) << 3) + hh);
      s16x8 vf0 = __builtin_shufflevector(lo0, hi0, 0, 1, 2, 3, 4, 5, 6, 7);
      s16x8 vf1 = __builtin_shufflevector(lo1, hi1, 0, 1, 2, 3, 4, 5, 6, 7);
      f32x4* on = (n == 0) ? &o0 : (n == 1) ? &o1 : (n == 2) ? &o2 : &o3;
      *on = __builtin_amdgcn_mfma_f32_16x16x32_bf16(pa0, vf0, *on, 0, 0, 0);
      *on = __builtin_amdgcn_mfma_f32_16x16x32_bf16(pa1, vf1, *on, 0, 0, 0);
    }

    if (t + 1 < NTH) {
      short* Kd = &Kt[cur ^ 1][0];
      short* Vd = &Vt[cur ^ 1][0];
      *(s16x8*)(Kd + sd0) = kst0;
      *(s16x8*)(Kd + sd1) = kst1;
      *(s16x8*)(Vd + sd0) = vst0;
      *(s16x8*)(Vd + sd1) = vst1;
    }
    __syncthreads();
    cur ^= 1;
  }

  float* Ob = O + ((long)(b * SS) + qr) * DD;
#pragma unroll
  for (int r = 0; r < 4; ++r) {
    int row = (g << 2) + r;
    atomicAdd(&Ob[row * DD +  0 + l15], o0[r]);
    atomicAdd(&Ob[row * DD + 16 + l15], o1[r]);
    atomicAdd(&Ob[row * DD + 32 + l15], o2[r]);
    atomicAdd(&Ob[row * DD + 48 + l15], o3[r]);
  }
}

extern "C" void kernel_launch(void* const* d_in, const int* in_sizes, int n_in,
                              void* d_out, int out_size, void* d_ws, size_t ws_size,
                              hipStream_t stream) {
  const float* q = (const float*)d_in[0];
  const float* k = (const float*)d_in[1];
  const float* v = (const float*)d_in[2];
  const unsigned char* mask = (const unsigned char*)d_in[3];

  const long BSD = (long)BB * SS * DD;            // 2M elems
  short* qn = (short*)d_ws;
  short* kn = qn + BSD;
  short* vtp = kn + BSD;
  unsigned short* bits = (unsigned short*)(vtp + BSD);             // 16 MB
  float* accG = (float*)(bits + (long)BB * SS * (SS / 16));        // 128 KB

  float* O = (float*)d_out;
  float* P = O + BSD;

  hipMemsetAsync(accG, 0, (size_t)BB * SS * sizeof(float), stream);
  hipMemsetAsync(O, 0, (size_t)BSD * sizeof(float), stream);

  k_norm<<<dim3(2 * BB * SS / 4), dim3(256), 0, stream>>>(q, k, qn, kn);
  k_vtrans<<<dim3(SS / 64, BB), dim3(256), 0, stream>>>(v, vtp);
  k_rowsum<<<dim3(2 * BB * SS / 64), dim3(256), 0, stream>>>(qn, kn, mask, bits, accG);
  k_attn<<<dim3(2 * BB * SS / 64), dim3(256), 0, stream>>>(qn, kn, vtp, bits, accG, O, P);
}

// Round 5
// 262.273 us; speedup vs baseline: 1.1877x; 1.1877x over previous
//
#include <hip/hip_runtime.h>
#include <math.h>

#define BB 8
#define SS 4096
#define DD 64
#define NTH 32   // k-tiles per half-sweep (64 k each)
#define LOG2E 1.4426950408889634f

typedef float  f32x4 __attribute__((ext_vector_type(4)));
typedef short  s16x4 __attribute__((ext_vector_type(4)));
typedef short  s16x8 __attribute__((ext_vector_type(8)));
typedef unsigned char u8x16 __attribute__((ext_vector_type(16)));

__device__ __forceinline__ short f2bf(float f) {
  unsigned u = __builtin_bit_cast(unsigned, f);
  u += 0x7FFFu + ((u >> 16) & 1u);
  return (short)(u >> 16);
}

// ---------------- kernel 1: L2-normalize q,k rows -> bf16 ----------------
// q additionally scaled by log2(e) so scores are in log2 domain (native v_exp).
__global__ __launch_bounds__(256) void k_norm(const float* __restrict__ q,
                                              const float* __restrict__ k,
                                              short* __restrict__ qn,
                                              short* __restrict__ kn) {
  const long BS = (long)BB * SS;
  long row = (long)blockIdx.x * 4 + (threadIdx.x >> 6);
  int lane = threadIdx.x & 63;
  const float* src;
  short* dst;
  float sc;
  if (row < BS) { src = q + row * DD; dst = qn + row * DD; sc = LOG2E; }
  else          { src = k + (row - BS) * DD; dst = kn + (row - BS) * DD; sc = 1.0f; }
  float x = src[lane];
  float ss = x * x;
#pragma unroll
  for (int m = 32; m >= 1; m >>= 1) ss += __shfl_xor(ss, m);
  float inv = sc / (sqrtf(ss) + 1e-10f);
  dst[lane] = f2bf(x * inv);
}

// ---------------- kernel 2: V -> VT[b][d][s] bf16 ; also zeroes O ----------------
__global__ __launch_bounds__(256) void k_vtrans(const float* __restrict__ v,
                                                short* __restrict__ vt,
                                                float* __restrict__ O) {
  __shared__ short tile[64][65];
  int b = blockIdx.y;
  int s0 = blockIdx.x * 64;
  const float* V = v + ((long)b * SS + s0) * DD;
  int t = threadIdx.x;
#pragma unroll
  for (int i = 0; i < 16; i++) {
    int flat = t + 256 * i;            // flat = sl*64 + d
    int sl = flat >> 6, d = flat & 63;
    tile[sl][d] = f2bf(V[flat]);
  }
  // zero O (2M floats, 512 blocks x 256 thr x 4 f32x4)
  {
    f32x4 z = {0.f, 0.f, 0.f, 0.f};
    f32x4* O4 = (f32x4*)O;
    long tid = (long)(blockIdx.y * gridDim.x + blockIdx.x) * 256 + t;
#pragma unroll
    for (int j = 0; j < 4; j++) O4[j * 131072 + tid] = z;
  }
  __syncthreads();
  short* VT = vt + (long)b * DD * SS + s0;
#pragma unroll
  for (int i = 0; i < 16; i++) {
    int flat = t + 256 * i;            // flat = d*64 + sl
    int d = flat >> 6, sl = flat & 63;
    VT[(long)d * SS + sl] = tile[sl][d];
  }
}

// ---------------- kernel 3: mask bytes -> bits (16x compress, linear) ----------------
__global__ __launch_bounds__(256) void k_maskbits(const unsigned char* __restrict__ m,
                                                  unsigned short* __restrict__ bits) {
  long gid = (long)blockIdx.x * 256 + threadIdx.x;
  u8x16 v = __builtin_nontemporal_load((const u8x16*)(m + gid * 16));
  unsigned r = 0;
#pragma unroll
  for (int i = 0; i < 16; i++) r |= (v[i] ? 1u : 0u) << i;
  __builtin_nontemporal_store((unsigned short)r, bits + gid);
}

// ------- pass A (k-split x2): partial exp row-sums -> accP[half] -------
__global__ __launch_bounds__(256) void k_rowsum(const short* __restrict__ qn,
                                                const short* __restrict__ kn,
                                                const unsigned short* __restrict__ bits,
                                                float* __restrict__ accP) {
  __shared__ __align__(16) short Kt[2][4096];
  int b = blockIdx.x & 7;
  int half = (blockIdx.x >> 3) & 1;
  int q0 = (blockIdx.x >> 4) << 6;
  int t0 = half * NTH;
  int wid = threadIdx.x >> 6, lane = threadIdx.x & 63;
  int l15 = lane & 15, g = lane >> 4;
  int qr = q0 + (wid << 4);

  const short* Qr = qn + ((long)(b * SS) + qr + l15) * DD;
  s16x8 qf0 = *(const s16x8*)(Qr + 8 * g);
  s16x8 qf1 = *(const s16x8*)(Qr + 32 + 8 * g);

  const short* Kb = kn + (long)b * SS * DD + (long)t0 * 64 * DD;
  const unsigned long long* B64 =
      (const unsigned long long*)bits + ((long)(b * SS) + qr + l15) * (SS / 64);

  int sr = lane >> 3, sc = lane & 7;
  int r0 = (wid << 4) + sr, r1 = r0 + 8;
  const short* Ksrc0 = Kb + (long)r0 * DD + sc * 8;
  const short* Ksrc1 = Kb + (long)r1 * DD + sc * 8;
  int kd0 = r0 * DD + ((sc ^ sr) << 3);
  int kd1 = r1 * DD + ((sc ^ sr) << 3);
  int swk = l15 & 7;

  s16x8 kst0 = *(const s16x8*)Ksrc0;
  s16x8 kst1 = *(const s16x8*)Ksrc1;
  *(s16x8*)&Kt[0][kd0] = kst0;
  *(s16x8*)&Kt[0][kd1] = kst1;
  __syncthreads();

  float acc = 0.f;
  int cur = 0;
  for (int t = 0; t < NTH; ++t) {
    if (t + 1 < NTH) {
      long koff = (long)(t + 1) * 64 * DD;
      kst0 = *(const s16x8*)(Ksrc0 + koff);
      kst1 = *(const s16x8*)(Ksrc1 + koff);
    }
    unsigned long long w64 = B64[t0 + t];
    const short* Kc = &Kt[cur][0];
#pragma unroll
    for (int tt = 0; tt < 4; ++tt) {
      const short* krow = Kc + ((tt << 4) + l15) * DD;
      s16x8 a0 = *(const s16x8*)(krow + ((g ^ swk) << 3));
      s16x8 a1 = *(const s16x8*)(krow + (((4 + g) ^ swk) << 3));
      f32x4 c = {0.f, 0.f, 0.f, 0.f};
      c = __builtin_amdgcn_mfma_f32_16x16x32_bf16(a0, qf0, c, 0, 0, 0);
      c = __builtin_amdgcn_mfma_f32_16x16x32_bf16(a1, qf1, c, 0, 0, 0);
#pragma unroll
      for (int r = 0; r < 4; ++r) {
        unsigned bit = (unsigned)(w64 >> ((tt << 4) + (g << 2) + r)) & 1u;
        acc += bit ? 0.f : exp2f(c[r]);
      }
    }
    if (t + 1 < NTH) {
      short* Kd = &Kt[cur ^ 1][0];
      *(s16x8*)(Kd + kd0) = kst0;
      *(s16x8*)(Kd + kd1) = kst1;
    }
    __syncthreads();
    cur ^= 1;
  }
  acc += __shfl_xor(acc, 16);
  acc += __shfl_xor(acc, 32);
  if (lane < 16)
    accP[(long)half * (BB * SS) + (long)b * SS + qr + l15] = acc;
}

// ------- pass B (k-split x2): recompute scores, write P, atomic O -------
__global__ __launch_bounds__(256) void k_attn(const short* __restrict__ qn,
                                              const short* __restrict__ kn,
                                              const short* __restrict__ vt,
                                              const unsigned short* __restrict__ bits,
                                              const float* __restrict__ accP,
                                              float* __restrict__ O,
                                              float* __restrict__ P) {
  __shared__ __align__(16) short Kt[2][4096];
  __shared__ __align__(16) short Vt[2][4096];
  int b = blockIdx.x & 7;
  int half = (blockIdx.x >> 3) & 1;
  int q0 = (blockIdx.x >> 4) << 6;
  int t0 = half * NTH;
  int wid = threadIdx.x >> 6, lane = threadIdx.x & 63;
  int l15 = lane & 15, g = lane >> 4;
  int qr = q0 + (wid << 4);

  const short* Qr = qn + ((long)(b * SS) + qr + l15) * DD;
  s16x8 qf0 = *(const s16x8*)(Qr + 8 * g);
  s16x8 qf1 = *(const s16x8*)(Qr + 32 + 8 * g);

  const short* Kb = kn + (long)b * SS * DD + (long)t0 * 64 * DD;
  const short* Vb = vt + (long)b * DD * SS + t0 * 64;
  const unsigned long long* B64 =
      (const unsigned long long*)bits + ((long)(b * SS) + qr + l15) * (SS / 64);
  long rowid = (long)b * SS + qr + l15;
  float linv2 = -__log2f(accP[rowid] + accP[(long)(BB * SS) + rowid]);
  float* Prow = P + rowid * SS;

  int sr = lane >> 3, sc = lane & 7;
  int r0 = (wid << 4) + sr, r1 = r0 + 8;
  const short* Ksrc0 = Kb + (long)r0 * DD + sc * 8;
  const short* Ksrc1 = Kb + (long)r1 * DD + sc * 8;
  const short* Vsrc0 = Vb + (long)r0 * SS + sc * 8;
  const short* Vsrc1 = Vb + (long)r1 * SS + sc * 8;
  int sd0 = r0 * DD + ((sc ^ sr) << 3);
  int sd1 = r1 * DD + ((sc ^ sr) << 3);
  int swk = l15 & 7;

  s16x8 kst0 = *(const s16x8*)Ksrc0;
  s16x8 kst1 = *(const s16x8*)Ksrc1;
  s16x8 vst0 = *(const s16x8*)Vsrc0;
  s16x8 vst1 = *(const s16x8*)Vsrc1;
  *(s16x8*)&Kt[0][sd0] = kst0;
  *(s16x8*)&Kt[0][sd1] = kst1;
  *(s16x8*)&Vt[0][sd0] = vst0;
  *(s16x8*)&Vt[0][sd1] = vst1;
  __syncthreads();

  f32x4 o0 = {0, 0, 0, 0}, o1 = {0, 0, 0, 0}, o2 = {0, 0, 0, 0}, o3 = {0, 0, 0, 0};
  int cur = 0;
  for (int t = 0; t < NTH; ++t) {
    if (t + 1 < NTH) {
      long koff = (long)(t + 1) * 64 * DD;
      kst0 = *(const s16x8*)(Ksrc0 + koff);
      kst1 = *(const s16x8*)(Ksrc1 + koff);
      vst0 = *(const s16x8*)(Vsrc0 + (t + 1) * 64);
      vst1 = *(const s16x8*)(Vsrc1 + (t + 1) * 64);
    }
    unsigned long long w64 = B64[t0 + t];
    const short* Kc = &Kt[cur][0];
    const short* Vc = &Vt[cur][0];

    f32x4 p[4];
#pragma unroll
    for (int tt = 0; tt < 4; ++tt) {
      const short* krow = Kc + ((tt << 4) + l15) * DD;
      s16x8 a0 = *(const s16x8*)(krow + ((g ^ swk) << 3));
      s16x8 a1 = *(const s16x8*)(krow + (((4 + g) ^ swk) << 3));
      f32x4 c = {0.f, 0.f, 0.f, 0.f};
      c = __builtin_amdgcn_mfma_f32_16x16x32_bf16(a0, qf0, c, 0, 0, 0);
      c = __builtin_amdgcn_mfma_f32_16x16x32_bf16(a1, qf1, c, 0, 0, 0);
#pragma unroll
      for (int r = 0; r < 4; ++r) {
        unsigned bit = (unsigned)(w64 >> ((tt << 4) + (g << 2) + r)) & 1u;
        p[tt][r] = bit ? 0.f : exp2f(c[r] + linv2);
      }
      __builtin_nontemporal_store(p[tt],
          (f32x4*)(Prow + ((t0 + t) << 6) + (tt << 4) + (g << 2)));
    }

    s16x8 pa0, pa1;
#pragma unroll
    for (int j = 0; j < 4; ++j) {
      pa0[j] = f2bf(p[0][j]); pa0[4 + j] = f2bf(p[1][j]);
      pa1[j] = f2bf(p[2][j]); pa1[4 + j] = f2bf(p[3][j]);
    }

#pragma unroll
    for (int n = 0; n < 4; ++n) {
      const short* vrow = Vc + ((n << 4) + l15) * DD;
      int g2 = g >> 1, hh = (g & 1) << 2;
      s16x4 lo0 = *(const s16x4*)(vrow + (((g2    ) ^ swk) << 3) + hh);
      s16x4 hi0 = *(const s16x4*)(vrow + (((g2 + 2) ^ swk) << 3) + hh);
      s16x4 lo1 = *(const s16x4*)(vrow + (((g2 + 4) ^ swk) << 3) + hh);
      s16x4 hi1 = *(const s16x4*)(vrow + (((g2 + 6) ^ swk) << 3) + hh);
      s16x8 vf0 = __builtin_shufflevector(lo0, hi0, 0, 1, 2, 3, 4, 5, 6, 7);
      s16x8 vf1 = __builtin_shufflevector(lo1, hi1, 0, 1, 2, 3, 4, 5, 6, 7);
      f32x4* on = (n == 0) ? &o0 : (n == 1) ? &o1 : (n == 2) ? &o2 : &o3;
      *on = __builtin_amdgcn_mfma_f32_16x16x32_bf16(pa0, vf0, *on, 0, 0, 0);
      *on = __builtin_amdgcn_mfma_f32_16x16x32_bf16(pa1, vf1, *on, 0, 0, 0);
    }

    if (t + 1 < NTH) {
      short* Kd = &Kt[cur ^ 1][0];
      short* Vd = &Vt[cur ^ 1][0];
      *(s16x8*)(Kd + sd0) = kst0;
      *(s16x8*)(Kd + sd1) = kst1;
      *(s16x8*)(Vd + sd0) = vst0;
      *(s16x8*)(Vd + sd1) = vst1;
    }
    __syncthreads();
    cur ^= 1;
  }

  // exactly 2 atomic contributions per address (half 0 + half 1): deterministic
  float* Ob = O + ((long)(b * SS) + qr) * DD;
#pragma unroll
  for (int r = 0; r < 4; ++r) {
    int row = (g << 2) + r;
    atomicAdd(&Ob[row * DD +  0 + l15], o0[r]);
    atomicAdd(&Ob[row * DD + 16 + l15], o1[r]);
    atomicAdd(&Ob[row * DD + 32 + l15], o2[r]);
    atomicAdd(&Ob[row * DD + 48 + l15], o3[r]);
  }
}

extern "C" void kernel_launch(void* const* d_in, const int* in_sizes, int n_in,
                              void* d_out, int out_size, void* d_ws, size_t ws_size,
                              hipStream_t stream) {
  const float* q = (const float*)d_in[0];
  const float* k = (const float*)d_in[1];
  const float* v = (const float*)d_in[2];
  const unsigned char* mask = (const unsigned char*)d_in[3];

  const long BSD = (long)BB * SS * DD;
  short* qn = (short*)d_ws;
  short* kn = qn + BSD;
  short* vtp = kn + BSD;
  unsigned short* bits = (unsigned short*)(vtp + BSD);      // 16 MB
  float* accP = (float*)(bits + (long)BB * SS * (SS / 16)); // 2 x 128 KB

  float* O = (float*)d_out;
  float* P = O + BSD;

  k_norm<<<dim3(2 * BB * SS / 4), dim3(256), 0, stream>>>(q, k, qn, kn);
  k_vtrans<<<dim3(SS / 64, BB), dim3(256), 0, stream>>>(v, vtp, O);
  k_maskbits<<<dim3((int)((long)BB * SS * SS / 16 / 256)), dim3(256), 0, stream>>>(mask, bits);
  k_rowsum<<<dim3(2 * BB * SS / 64), dim3(256), 0, stream>>>(qn, kn, bits, accP);
  k_attn<<<dim3(2 * BB * SS / 64), dim3(256), 0, stream>>>(qn, kn, vtp, bits, accP, O, P);
}